// Round 4
// baseline (915.990 us; speedup 1.0000x reference)
//
#include <hip/hip_runtime.h>
#include <stdint.h>

// SpikingLinearLayer: spikes = LIF_scan(x @ W^T)  -- exact i8-limb MFMA path.
//   x: [20, 1024, 2048] fp32 binary; W: [2048, 2048] fp32; out fp32 binary.
//
// R7 -> R8: retreat to R4's replay-proven region structure; attack OCCUPANCY.
//  * R7 (phase template, hand vmcnt/barriers) raced on warm graph replays --
//    reverted entirely. R8 has NO inline asm, no setprio: staging is all
//    global_load_lds, one __syncthreads() per region (compiler-managed
//    drains), exactly the R4 synchronization that passed 4 sessions.
//  * Lever: R4 was pinned at 2 waves/SIMD (128 VGPR + 128 AGPR acc = 256
//    combined). Tile now 64b x 32o, each wave owns 32b x 16o x 2t:
//    acc = 16 v4i = 64 AGPR, LIF = V[8]/I[8] = 32 VGPR -> combined ~160,
//    __launch_bounds__(256,3) -> 3 blocks/CU = 3 waves/SIMD (+50% issue
//    slots, 3 independent barrier domains per CU to hide region stalls).
//  * LDS/buffer: A 2t x 4KB + B 4 planes x 2KB = 16KB; dbuf 32KB; x3 = 96KB.
//  * Grid 1024, XCD swizzle: 8 o-tiles per XCD -> limb slice 2MB per L2.

constexpr int T_STEPS = 20;
constexpr int BATCH   = 1024;
constexpr int NIN     = 2048;
constexpr int NOUT    = 2048;

constexpr int    Q         = 4;
constexpr double SCALE     = 1073741824.0;     // 2^30
constexpr double INV_SCALE = 1.0 / SCALE;

constexpr size_t XI8_BYTES   = (size_t)T_STEPS * BATCH * NIN;        // 40 MB
constexpr size_t PLANE_BYTES = (size_t)NOUT * NIN;                   // 4 MB
constexpr size_t WS_NEEDED   = XI8_BYTES + (size_t)Q * PLANE_BYTES;  // 56 MB

typedef int v4i __attribute__((ext_vector_type(4)));

// async 16B/lane global->LDS DMA: lds dst = uniform base + lane*16
__device__ __forceinline__ void dma16(const int8_t* g, const int8_t* l) {
    __builtin_amdgcn_global_load_lds(
        (const __attribute__((address_space(1))) void*)(uintptr_t)g,
        (__attribute__((address_space(3))) void*)(uint32_t)(uintptr_t)l,
        16, 0, 0);
}

// ---------------------------------------------------------------- prep: x -> i8
__global__ void prep_x(const float* __restrict__ x, int8_t* __restrict__ xi) {
    const int idx = blockIdx.x * blockDim.x + threadIdx.x;   // 16 elems each
    const float4* xg = reinterpret_cast<const float4*>(x) + idx * 4;
    int8_t c[16];
#pragma unroll
    for (int q = 0; q < 4; ++q) {
        const float4 v = xg[q];
        c[q * 4 + 0] = (int8_t)(v.x != 0.0f);
        c[q * 4 + 1] = (int8_t)(v.y != 0.0f);
        c[q * 4 + 2] = (int8_t)(v.z != 0.0f);
        c[q * 4 + 3] = (int8_t)(v.w != 0.0f);
    }
    reinterpret_cast<v4i*>(xi)[idx] = *reinterpret_cast<const v4i*>(c);
}

// ------------------------------------------------- prep: W -> 4 base-256 digits
__global__ void prep_limbs(const float* __restrict__ w, int8_t* __restrict__ limbs) {
    const int idx = blockIdx.x * blockDim.x + threadIdx.x;   // 4 weights each
    const float4 wv = reinterpret_cast<const float4*>(w)[idx];
    const float wf[4] = {wv.x, wv.y, wv.z, wv.w};
    int8_t d[Q][4];
#pragma unroll
    for (int e = 0; e < 4; ++e) {
        long long M = llrint((double)wf[e] * SCALE);         // |M| < 2^30
#pragma unroll
        for (int j = 0; j < Q - 1; ++j) {
            const int dj = (int)((M + 128) & 255) - 128;
            d[j][e] = (int8_t)dj;
            M = (M - dj) >> 8;                               // exact
        }
        d[Q - 1][e] = (int8_t)M;                             // |top| <= 65
    }
#pragma unroll
    for (int j = 0; j < Q; ++j)
        reinterpret_cast<char4*>(limbs + (size_t)j * PLANE_BYTES)[idx] =
            make_char4(d[j][0], d[j][1], d[j][2], d[j][3]);
}

// --------------------------------------------------------------- hot: i8 GEMMs
constexpr int KC     = 64;
constexpr int NKC    = NIN / KC;            // 32
constexpr int NTB    = T_STEPS / 2;         // 10 t-pairs
constexpr int NITER  = NTB * NKC;           // 320
constexpr int BM     = 64;                  // batch tile
constexpr int BO     = 32;                  // out tile
constexpr int A_OFF  = 0;                   // A[t] at t*4096   (8 KB)
constexpr int B_OFF  = 8192;                // B[j] at j*2048   (8 KB)
constexpr int BUF_B  = 16384;

__global__ __launch_bounds__(256, 3)
void snn_i8(const int8_t* __restrict__ xi, const int8_t* __restrict__ limbs,
            float* __restrict__ out)
{
    // XCD swizzle: 8 o-tiles pinned per XCD -> limb slice 8*256KB = 2MB in L2
    const int bid   = blockIdx.x;            // 1024 blocks
    const int xcd   = bid & 7;
    const int sub   = bid >> 3;              // 0..127
    const int otile = xcd * 8 + (sub & 7);   // 0..63
    const int btile = sub >> 3;              // 0..15
    const int o0 = otile * BO, b0 = btile * BM;

    const int tid = threadIdx.x;
    const int w   = tid >> 6;                // wave 0..3
    const int ln  = tid & 63;
    const int lm  = ln & 15;
    const int qd  = ln >> 4;
    const int wm  = w >> 1;                  // batch half (32 rows)
    const int wn  = w & 1;                   // out half  (16 cols)

    __shared__ __align__(16) int8_t lds[2][BUF_B];   // 32 KB -> 3 blocks/CU

    // A staging: wave w deposits rows [b0+16w, +16) per t-half
    const size_t x_lane = (size_t)(b0 + 16 * w + lm) * NIN + qd * 16;
    // B staging: wave w deposits plane w, halves 0/1 (rows o0.. / o0+16..)
    const size_t bl0 = (size_t)w * PLANE_BYTES + (size_t)(o0 + lm) * NIN + qd * 16;
    const size_t bl1 = bl0 + (size_t)16 * NIN;

    // LIF state: e = mg*4+r -> b = b0+32wm+16mg+4qd+r, o = o0+16wn+lm
    double V[8], I[8];
#pragma unroll
    for (int e = 0; e < 8; ++e) { V[e] = 0.0; I[e] = 0.0; }

    const double alpha_m = 1.0 - 1.0 / 20.0;
    const double alpha_s = 1.0 - 1.0 / 5.0;
    const double dtm     = 1.0 / 20.0;

    // stage iter s into lds[s&1]; 4 DMAs per wave (A t0, A t1, B half0/1)
    auto stage = [&](int s) {
        const int tb = s >> 5;
        const int kc = (s & 31) << 6;
        const int8_t* xb = xi + (size_t)(2 * tb) * BATCH * NIN + kc + x_lane;
        int8_t* lb = &lds[s & 1][0];
        dma16(xb,                       lb + A_OFF + 0    + w * 1024);
        dma16(xb + (size_t)BATCH * NIN, lb + A_OFF + 4096 + w * 1024);
        dma16(limbs + bl0 + kc,         lb + B_OFF + w * 2048);
        dma16(limbs + bl1 + kc,         lb + B_OFF + w * 2048 + 1024);
    };

    stage(0);
    __syncthreads();

    int s = 0;
    for (int tb = 0; tb < NTB; ++tb) {
        v4i acc0[2][4], acc1[2][4];   // [mg][plane]
#pragma unroll
        for (int mg = 0; mg < 2; ++mg)
#pragma unroll
            for (int j = 0; j < Q; ++j) {
                acc0[mg][j] = (v4i){0, 0, 0, 0};
                acc1[mg][j] = (v4i){0, 0, 0, 0};
            }

        for (int kci = 0; kci < NKC; ++kci, ++s) {
            if (s + 1 < NITER) stage(s + 1);            // async prefetch

            const int8_t* cb = &lds[s & 1][0];
            v4i B[4];
#pragma unroll
            for (int j = 0; j < Q; ++j)
                B[j] = *reinterpret_cast<const v4i*>(
                    cb + B_OFF + j * 2048 + wn * 1024 + ln * 16);
#pragma unroll
            for (int mg = 0; mg < 2; ++mg) {
                const int g = 2 * wm + mg;
                const v4i A0 = *reinterpret_cast<const v4i*>(
                    cb + A_OFF + 0    + g * 1024 + ln * 16);
                const v4i A1 = *reinterpret_cast<const v4i*>(
                    cb + A_OFF + 4096 + g * 1024 + ln * 16);
#pragma unroll
                for (int j = 0; j < Q; ++j) {
                    acc0[mg][j] = __builtin_amdgcn_mfma_i32_16x16x64_i8(
                        A0, B[j], acc0[mg][j], 0, 0, 0);
                    acc1[mg][j] = __builtin_amdgcn_mfma_i32_16x16x64_i8(
                        A1, B[j], acc1[mg][j], 0, 0, 0);
                }
            }
            __syncthreads();   // drains DMA (already landed under the MFMAs)
        }

        // recombine digits (exact fp64), LIF, emit spikes for t-pair
        const int ocol = o0 + 16 * wn + lm;
#pragma unroll
        for (int tt = 0; tt < 2; ++tt) {
            const int t = 2 * tb + tt;
#pragma unroll
            for (int mg = 0; mg < 2; ++mg) {
#pragma unroll
                for (int r = 0; r < 4; ++r) {
                    const int d0 = tt ? acc1[mg][0][r] : acc0[mg][0][r];
                    const int d1 = tt ? acc1[mg][1][r] : acc0[mg][1][r];
                    const int d2 = tt ? acc1[mg][2][r] : acc0[mg][2][r];
                    const int d3 = tt ? acc1[mg][3][r] : acc0[mg][3][r];
                    double sm = (double)d3;
                    sm = sm * 256.0 + (double)d2;
                    sm = sm * 256.0 + (double)d1;
                    sm = sm * 256.0 + (double)d0;
                    const double cur = sm * INV_SCALE;

                    const int e = mg * 4 + r;
                    I[e] = alpha_s * I[e] + cur;
                    V[e] = alpha_m * V[e] + dtm * I[e];
                    const double sp = (V[e] >= 1.0) ? 1.0 : 0.0;
                    V[e] *= (1.0 - sp);

                    const int brow = b0 + 32 * wm + 16 * mg + 4 * qd + r;
                    __builtin_nontemporal_store(
                        (float)sp,
                        out + (size_t)t * BATCH * NOUT
                            + (size_t)brow * NOUT + ocol);
                }
            }
        }
    }
}

// ------------------------------------------------ fallback: verified R1 kernel
constexpr int TBF = 64, TOF = 64, KCF = 64, LDPF = KCF + 4;

__global__ __launch_bounds__(256, 2)
void snn_fused(const float* __restrict__ x,
               const float* __restrict__ w,
               float* __restrict__ out)
{
    const int o0  = blockIdx.x * TOF;
    const int b0  = blockIdx.y * TBF;
    const int tid = threadIdx.x;
    const int tx  = tid & 15;
    const int ty  = tid >> 4;

    __shared__ float xs[TBF][LDPF];
    __shared__ float ws[TOF][LDPF];

    const int lr = tid >> 2;
    const int lc = (tid & 3) << 4;

    double V[4][4], I[4][4];
#pragma unroll
    for (int i = 0; i < 4; ++i)
#pragma unroll
        for (int j = 0; j < 4; ++j) { V[i][j] = 0.0; I[i][j] = 0.0; }

    const double alpha_m = 1.0 - 1.0 / 20.0;
    const double alpha_s = 1.0 - 1.0 / 5.0;
    const double dtm     = 1.0 / 20.0;

    for (int t = 0; t < T_STEPS; ++t) {
        const float* xt = x + (size_t)t * BATCH * NIN;
        double c[4][4];
#pragma unroll
        for (int i = 0; i < 4; ++i)
#pragma unroll
            for (int j = 0; j < 4; ++j) c[i][j] = 0.0;

        for (int kc = 0; kc < NIN; kc += KCF) {
            __syncthreads();
            {
                const float4* xg = reinterpret_cast<const float4*>(
                    xt + (size_t)(b0 + lr) * NIN + kc + lc);
                const float4* wg = reinterpret_cast<const float4*>(
                    w + (size_t)(o0 + lr) * NIN + kc + lc);
#pragma unroll
                for (int q = 0; q < 4; ++q) {
                    float4 xv = xg[q];
                    float4 wv4 = wg[q];
                    const int cbi = lc + q * 4;
                    xs[lr][cbi + 0] = xv.x;  xs[lr][cbi + 1] = xv.y;
                    xs[lr][cbi + 2] = xv.z;  xs[lr][cbi + 3] = xv.w;
                    ws[lr][cbi + 0] = wv4.x; ws[lr][cbi + 1] = wv4.y;
                    ws[lr][cbi + 2] = wv4.z; ws[lr][cbi + 3] = wv4.w;
                }
            }
            __syncthreads();

#pragma unroll 8
            for (int k = 0; k < KCF; ++k) {
                float xa[4], wa[4];
#pragma unroll
                for (int i = 0; i < 4; ++i) xa[i] = xs[ty * 4 + i][k];
#pragma unroll
                for (int j = 0; j < 4; ++j) wa[j] = ws[tx * 4 + j][k];
#pragma unroll
                for (int i = 0; i < 4; ++i)
#pragma unroll
                    for (int j = 0; j < 4; ++j)
                        c[i][j] += (double)xa[i] * (double)wa[j];
            }
        }

#pragma unroll
        for (int i = 0; i < 4; ++i) {
            float sv[4];
#pragma unroll
            for (int j = 0; j < 4; ++j) {
                I[i][j] = alpha_s * I[i][j] + c[i][j];
                V[i][j] = alpha_m * V[i][j] + dtm * I[i][j];
                const double sp = (V[i][j] >= 1.0) ? 1.0 : 0.0;
                V[i][j] *= (1.0 - sp);
                sv[j] = (float)sp;
            }
            const size_t oidx = (size_t)t * BATCH * NOUT
                              + (size_t)(b0 + ty * 4 + i) * NOUT
                              + (size_t)(o0 + tx * 4);
            *reinterpret_cast<float4*>(out + oidx) =
                make_float4(sv[0], sv[1], sv[2], sv[3]);
        }
    }
}

extern "C" void kernel_launch(void* const* d_in, const int* in_sizes, int n_in,
                              void* d_out, int out_size, void* d_ws, size_t ws_size,
                              hipStream_t stream) {
    const float* x = (const float*)d_in[0];
    const float* w = (const float*)d_in[1];
    float* out     = (float*)d_out;
    (void)in_sizes; (void)n_in; (void)out_size;

    if (ws_size >= WS_NEEDED) {
        int8_t* xi    = (int8_t*)d_ws;
        int8_t* limbs = xi + XI8_BYTES;
        prep_x<<<(int)(XI8_BYTES / 16 / 256), 256, 0, stream>>>(x, xi);
        prep_limbs<<<(int)(PLANE_BYTES / 4 / 256), 256, 0, stream>>>(w, limbs);
        snn_i8<<<1024, 256, 0, stream>>>(xi, limbs, out);
    } else {
        dim3 grid(NOUT / TOF, BATCH / TBF);
        snn_fused<<<grid, dim3(256), 0, stream>>>(x, w, out);
    }
}

// Round 5
// 767.886 us; speedup vs baseline: 1.1929x; 1.1929x over previous
//
#include <hip/hip_runtime.h>
#include <stdint.h>

// SpikingLinearLayer: spikes = LIF_scan(x @ W^T)  -- exact i8-limb MFMA path.
//   x: [20, 1024, 2048] fp32 binary; W: [2048, 2048] fp32; out fp32 binary.
//
// R8 -> R9: scale the REGION, not its contents.
//  * R4/R5/R6/R8 post-mortem: barrier-to-barrier region wall is ~3700-4000cyc
//    regardless of contents (32 vs 16 MFMAs, B via LDS vs L2, prefetch or
//    not) -- a lockstep sync quantum (m233 signature). Total = #regions x
//    quantum. So: KC 64 -> 256, NITER 320 -> 80. 4x MFMA work fills each
//    quantum; barrier count drops 4x.
//  * Sync structure is EXACTLY R4's replay-proven one: all staging via
//    global_load_lds, ONE __syncthreads() per region (compiler-managed
//    drains), no inline asm, no setprio.
//  * A: 8 DMAs/wave/region into 32KB buffer; double-buffered = 64KB/block,
//    2 blocks/CU = 128KB <= 160. B: direct L2->VGPR per k-sub-chunk (R5-
//    proven addressing; B tile at KC=256 would not fit LDS).
//  * Fragment layouts byte-identical to the verified R4/R5 ones.

constexpr int T_STEPS = 20;
constexpr int BATCH   = 1024;
constexpr int NIN     = 2048;
constexpr int NOUT    = 2048;

constexpr int    Q         = 4;
constexpr double SCALE     = 1073741824.0;     // 2^30
constexpr double INV_SCALE = 1.0 / SCALE;

constexpr size_t XI8_BYTES   = (size_t)T_STEPS * BATCH * NIN;        // 40 MB
constexpr size_t PLANE_BYTES = (size_t)NOUT * NIN;                   // 4 MB
constexpr size_t WS_NEEDED   = XI8_BYTES + (size_t)Q * PLANE_BYTES;  // 56 MB

typedef int v4i __attribute__((ext_vector_type(4)));

// async 16B/lane global->LDS DMA: lds dst = uniform base + lane*16
__device__ __forceinline__ void dma16(const int8_t* g, const int8_t* l) {
    __builtin_amdgcn_global_load_lds(
        (const __attribute__((address_space(1))) void*)(uintptr_t)g,
        (__attribute__((address_space(3))) void*)(uint32_t)(uintptr_t)l,
        16, 0, 0);
}

// ---------------------------------------------------------------- prep: x -> i8
__global__ void prep_x(const float* __restrict__ x, int8_t* __restrict__ xi) {
    const int idx = blockIdx.x * blockDim.x + threadIdx.x;   // 16 elems each
    const float4* xg = reinterpret_cast<const float4*>(x) + idx * 4;
    int8_t c[16];
#pragma unroll
    for (int q = 0; q < 4; ++q) {
        const float4 v = xg[q];
        c[q * 4 + 0] = (int8_t)(v.x != 0.0f);
        c[q * 4 + 1] = (int8_t)(v.y != 0.0f);
        c[q * 4 + 2] = (int8_t)(v.z != 0.0f);
        c[q * 4 + 3] = (int8_t)(v.w != 0.0f);
    }
    reinterpret_cast<v4i*>(xi)[idx] = *reinterpret_cast<const v4i*>(c);
}

// ------------------------------------------------- prep: W -> 4 base-256 digits
__global__ void prep_limbs(const float* __restrict__ w, int8_t* __restrict__ limbs) {
    const int idx = blockIdx.x * blockDim.x + threadIdx.x;   // 4 weights each
    const float4 wv = reinterpret_cast<const float4*>(w)[idx];
    const float wf[4] = {wv.x, wv.y, wv.z, wv.w};
    int8_t d[Q][4];
#pragma unroll
    for (int e = 0; e < 4; ++e) {
        long long M = llrint((double)wf[e] * SCALE);         // |M| < 2^30
#pragma unroll
        for (int j = 0; j < Q - 1; ++j) {
            const int dj = (int)((M + 128) & 255) - 128;
            d[j][e] = (int8_t)dj;
            M = (M - dj) >> 8;                               // exact
        }
        d[Q - 1][e] = (int8_t)M;                             // |top| <= 65
    }
#pragma unroll
    for (int j = 0; j < Q; ++j)
        reinterpret_cast<char4*>(limbs + (size_t)j * PLANE_BYTES)[idx] =
            make_char4(d[j][0], d[j][1], d[j][2], d[j][3]);
}

// --------------------------------------------------------------- hot: i8 GEMMs
constexpr int KC     = 256;                 // K per region (4 x 64-sub-chunks)
constexpr int NKC    = NIN / KC;            // 8 regions per t-pair
constexpr int NTB    = T_STEPS / 2;         // 10 t-pairs
constexpr int NITER  = NTB * NKC;           // 80 regions total
constexpr int ABUF   = 32768;               // per buffer: 2t x 4 chunks x 4 KB

__global__ __launch_bounds__(256, 2)
void snn_i8(const int8_t* __restrict__ xi, const int8_t* __restrict__ limbs,
            float* __restrict__ out)
{
    // XCD swizzle: 4 o-tiles pinned per XCD -> limb set 4*512KB = 2MB in 4MB L2
    const int bid   = blockIdx.x;            // 512 blocks
    const int xcd   = bid & 7;
    const int sub   = bid >> 3;
    const int otile = xcd * 4 + (sub & 3);
    const int btile = sub >> 2;
    const int o0 = otile * 64, b0 = btile * 64;

    const int tid  = threadIdx.x;
    const int w    = tid >> 6;     // wave id: o j-group owner + stage group
    const int ln   = tid & 63;
    const int lm   = ln & 15;
    const int qd   = ln >> 4;

    __shared__ __align__(16) int8_t lds[2][ABUF];   // 64 KB -> 2 blocks/CU

    // per-lane global byte offsets (DMA deposits at base + ln*16)
    const size_t x_lane = (size_t)(b0 + 16 * w + lm) * NIN + qd * 16;
    const size_t l_lane = (size_t)(o0 + 16 * w + lm) * NIN + qd * 16;
    const int8_t* bbase = limbs + l_lane;   // B fragments direct from L2

    // LIF state: lane elems e = mg*4+r -> b = b0+16mg+4qd+r, o = o0+16w+lm
    double V[16], I[16];
#pragma unroll
    for (int e = 0; e < 16; ++e) { V[e] = 0.0; I[e] = 0.0; }

    const double alpha_m = 1.0 - 1.0 / 20.0;
    const double alpha_s = 1.0 - 1.0 / 5.0;
    const double dtm     = 1.0 / 20.0;

    // stage region s into lds[s&1]: 8 DMAs/wave (2 t-halves x 4 k-chunks).
    // LDS layout: [th][chunk][group w][slot ln] -> th*16384+c*4096+w*1024+ln*16
    auto stage = [&](int s) {
        const int tb = s >> 3;               // t-pair
        const int kc = (s & 7) << 8;         // K offset (256 per region)
        const int8_t* xb = xi + (size_t)(2 * tb) * BATCH * NIN + kc + x_lane;
        int8_t* lb = &lds[s & 1][0];
#pragma unroll
        for (int th = 0; th < 2; ++th)
#pragma unroll
            for (int c = 0; c < 4; ++c)
                dma16(xb + (size_t)th * BATCH * NIN + c * 64,
                      lb + th * 16384 + c * 4096 + w * 1024);
    };

    stage(0);
    __syncthreads();

    int s = 0;
    for (int tb = 0; tb < NTB; ++tb) {
        v4i acc0[4][4], acc1[4][4];   // [mg][plane]
#pragma unroll
        for (int mg = 0; mg < 4; ++mg)
#pragma unroll
            for (int j = 0; j < Q; ++j) {
                acc0[mg][j] = (v4i){0, 0, 0, 0};
                acc1[mg][j] = (v4i){0, 0, 0, 0};
            }

        for (int kci = 0; kci < NKC; ++kci, ++s) {
            if (s + 1 < NITER) stage(s + 1);            // async prefetch

            const int8_t* cb = &lds[s & 1][0];
            const int kc = (s & 7) << 8;
#pragma unroll
            for (int ksc = 0; ksc < 4; ++ksc) {
                // B fragments for this 64-k sub-chunk, straight from L2
                v4i B[4];
#pragma unroll
                for (int j = 0; j < Q; ++j)
                    B[j] = *reinterpret_cast<const v4i*>(
                        bbase + (size_t)j * PLANE_BYTES + kc + ksc * 64);
#pragma unroll
                for (int mg = 0; mg < 4; ++mg) {
                    const v4i A0 = *reinterpret_cast<const v4i*>(
                        cb + 0     + ksc * 4096 + mg * 1024 + ln * 16);
                    const v4i A1 = *reinterpret_cast<const v4i*>(
                        cb + 16384 + ksc * 4096 + mg * 1024 + ln * 16);
#pragma unroll
                    for (int j = 0; j < Q; ++j) {
                        acc0[mg][j] = __builtin_amdgcn_mfma_i32_16x16x64_i8(
                            A0, B[j], acc0[mg][j], 0, 0, 0);
                        acc1[mg][j] = __builtin_amdgcn_mfma_i32_16x16x64_i8(
                            A1, B[j], acc1[mg][j], 0, 0, 0);
                    }
                }
            }
            __syncthreads();   // drains DMA (landed under 128 MFMAs)
        }

        // recombine digits (exact fp64), LIF, emit spikes for t-pair
        const int ocol = o0 + 16 * w + lm;
#pragma unroll
        for (int tt = 0; tt < 2; ++tt) {
            const int t = 2 * tb + tt;
#pragma unroll
            for (int mg = 0; mg < 4; ++mg) {
#pragma unroll
                for (int r = 0; r < 4; ++r) {
                    const int d0 = tt ? acc1[mg][0][r] : acc0[mg][0][r];
                    const int d1 = tt ? acc1[mg][1][r] : acc0[mg][1][r];
                    const int d2 = tt ? acc1[mg][2][r] : acc0[mg][2][r];
                    const int d3 = tt ? acc1[mg][3][r] : acc0[mg][3][r];
                    double sm = (double)d3;
                    sm = sm * 256.0 + (double)d2;
                    sm = sm * 256.0 + (double)d1;
                    sm = sm * 256.0 + (double)d0;
                    const double cur = sm * INV_SCALE;

                    const int e = mg * 4 + r;
                    I[e] = alpha_s * I[e] + cur;
                    V[e] = alpha_m * V[e] + dtm * I[e];
                    const double sp = (V[e] >= 1.0) ? 1.0 : 0.0;
                    V[e] *= (1.0 - sp);

                    const int brow = b0 + 16 * mg + 4 * qd + r;
                    __builtin_nontemporal_store(
                        (float)sp,
                        out + (size_t)t * BATCH * NOUT
                            + (size_t)brow * NOUT + ocol);
                }
            }
        }
    }
}

// ------------------------------------------------ fallback: verified R1 kernel
constexpr int TBF = 64, TOF = 64, KCF = 64, LDPF = KCF + 4;

__global__ __launch_bounds__(256, 2)
void snn_fused(const float* __restrict__ x,
               const float* __restrict__ w,
               float* __restrict__ out)
{
    const int o0  = blockIdx.x * TOF;
    const int b0  = blockIdx.y * TBF;
    const int tid = threadIdx.x;
    const int tx  = tid & 15;
    const int ty  = tid >> 4;

    __shared__ float xs[TBF][LDPF];
    __shared__ float ws[TOF][LDPF];

    const int lr = tid >> 2;
    const int lc = (tid & 3) << 4;

    double V[4][4], I[4][4];
#pragma unroll
    for (int i = 0; i < 4; ++i)
#pragma unroll
        for (int j = 0; j < 4; ++j) { V[i][j] = 0.0; I[i][j] = 0.0; }

    const double alpha_m = 1.0 - 1.0 / 20.0;
    const double alpha_s = 1.0 - 1.0 / 5.0;
    const double dtm     = 1.0 / 20.0;

    for (int t = 0; t < T_STEPS; ++t) {
        const float* xt = x + (size_t)t * BATCH * NIN;
        double c[4][4];
#pragma unroll
        for (int i = 0; i < 4; ++i)
#pragma unroll
            for (int j = 0; j < 4; ++j) c[i][j] = 0.0;

        for (int kc = 0; kc < NIN; kc += KCF) {
            __syncthreads();
            {
                const float4* xg = reinterpret_cast<const float4*>(
                    xt + (size_t)(b0 + lr) * NIN + kc + lc);
                const float4* wg = reinterpret_cast<const float4*>(
                    w + (size_t)(o0 + lr) * NIN + kc + lc);
#pragma unroll
                for (int q = 0; q < 4; ++q) {
                    float4 xv = xg[q];
                    float4 wv4 = wg[q];
                    const int cbi = lc + q * 4;
                    xs[lr][cbi + 0] = xv.x;  xs[lr][cbi + 1] = xv.y;
                    xs[lr][cbi + 2] = xv.z;  xs[lr][cbi + 3] = xv.w;
                    ws[lr][cbi + 0] = wv4.x; ws[lr][cbi + 1] = wv4.y;
                    ws[lr][cbi + 2] = wv4.z; ws[lr][cbi + 3] = wv4.w;
                }
            }
            __syncthreads();

#pragma unroll 8
            for (int k = 0; k < KCF; ++k) {
                float xa[4], wa[4];
#pragma unroll
                for (int i = 0; i < 4; ++i) xa[i] = xs[ty * 4 + i][k];
#pragma unroll
                for (int j = 0; j < 4; ++j) wa[j] = ws[tx * 4 + j][k];
#pragma unroll
                for (int i = 0; i < 4; ++i)
#pragma unroll
                    for (int j = 0; j < 4; ++j)
                        c[i][j] += (double)xa[i] * (double)wa[j];
            }
        }

#pragma unroll
        for (int i = 0; i < 4; ++i) {
            float sv[4];
#pragma unroll
            for (int j = 0; j < 4; ++j) {
                I[i][j] = alpha_s * I[i][j] + c[i][j];
                V[i][j] = alpha_m * V[i][j] + dtm * I[i][j];
                const double sp = (V[i][j] >= 1.0) ? 1.0 : 0.0;
                V[i][j] *= (1.0 - sp);
                sv[j] = (float)sp;
            }
            const size_t oidx = (size_t)t * BATCH * NOUT
                              + (size_t)(b0 + ty * 4 + i) * NOUT
                              + (size_t)(o0 + tx * 4);
            *reinterpret_cast<float4*>(out + oidx) =
                make_float4(sv[0], sv[1], sv[2], sv[3]);
        }
    }
}

extern "C" void kernel_launch(void* const* d_in, const int* in_sizes, int n_in,
                              void* d_out, int out_size, void* d_ws, size_t ws_size,
                              hipStream_t stream) {
    const float* x = (const float*)d_in[0];
    const float* w = (const float*)d_in[1];
    float* out     = (float*)d_out;
    (void)in_sizes; (void)n_in; (void)out_size;

    if (ws_size >= WS_NEEDED) {
        int8_t* xi    = (int8_t*)d_ws;
        int8_t* limbs = xi + XI8_BYTES;
        prep_x<<<(int)(XI8_BYTES / 16 / 256), 256, 0, stream>>>(x, xi);
        prep_limbs<<<(int)(PLANE_BYTES / 4 / 256), 256, 0, stream>>>(w, limbs);
        snn_i8<<<512, 256, 0, stream>>>(xi, limbs, out);
    } else {
        dim3 grid(NOUT / TOF, BATCH / TBF);
        snn_fused<<<grid, dim3(256), 0, stream>>>(x, w, out);
    }
}